// Round 8
// baseline (855.593 us; speedup 1.0000x reference)
//
#include <hip/hip_runtime.h>

// QuantizedLinear M=8192 K=4096 N=11008.
// Prepass (fused): dequant int4-blockwise W -> f16 [N][K]; cvt x -> f16 [M][K].
// GEMM: 256x256 tile, BK=64, 512 thr (8 waves 2Mx4N), mfma_f32_32x32x16_f16,
// 4-phase/K-tile: [6x ds_read burst][1 stage][barrier][lgkmcnt(0)][8x MFMA][ph3: vmcnt(6)][barrier].
// Stage plan (race-free: no phase stages a half-slot it reads):
//   ph0 -> Bhi[t+1] (parity pn, untouched by tile t); ph1 -> Alo[t+2]; ph2 -> Ahi[t+2]
//   (A 3-parity ring, untouched parity); ph3 -> Blo[t+2] (B[p][kk0], last read ph1).
// Single vmcnt(6) at ph3 confirms {Alo,Ahi,Blo,Bhi}[t+1]. A3+B2 rings = 160KB LDS.

#define K_DIM 4096
#define N_DIM 11008
#define M_DIM 8192
#define NT_K 64       // K_DIM / 64
#define AB_OFF 98304  // A region [0,98304): 3 parities x 32KB; B region: 2 parities x 32KB

typedef _Float16 f16;
typedef _Float16 f16x8 __attribute__((ext_vector_type(8)));
typedef float f32x16 __attribute__((ext_vector_type(16)));
typedef float fv4 __attribute__((ext_vector_type(4)));
typedef int iv4 __attribute__((ext_vector_type(4)));

__device__ __forceinline__ void gload16(const void* g, void* lds) {
  __builtin_amdgcn_global_load_lds(
      (__attribute__((address_space(1))) void*)g,
      (__attribute__((address_space(3))) void*)lds,
      16, 0, 0);
}

// fused prepass: threads [0,n8x) convert x (f32->f16, 8/thread); rest dequant W (8/thread).
__global__ __launch_bounds__(256) void prep_kernel(const float* __restrict__ x,
                                                   f16* __restrict__ xo, int n8x,
                                                   const int* __restrict__ q,
                                                   const float* __restrict__ amax,
                                                   f16* __restrict__ wo, int n8w) {
  int i = blockIdx.x * blockDim.x + threadIdx.x;
  if (i < n8x) {
    const fv4* xv = (const fv4*)x;
    fv4 a = __builtin_nontemporal_load(xv + 2 * (size_t)i);
    fv4 b = __builtin_nontemporal_load(xv + 2 * (size_t)i + 1);
    f16x8 o;
    o[0] = (f16)a.x; o[1] = (f16)a.y; o[2] = (f16)a.z; o[3] = (f16)a.w;
    o[4] = (f16)b.x; o[5] = (f16)b.y; o[6] = (f16)b.z; o[7] = (f16)b.w;
    *(f16x8*)(xo + (size_t)i * 8) = o;
  } else {
    int j = i - n8x;
    if (j >= n8w) return;
    const iv4* qv = (const iv4*)q;
    iv4 a = __builtin_nontemporal_load(qv + 2 * (size_t)j);
    iv4 b = __builtin_nontemporal_load(qv + 2 * (size_t)j + 1);
    float s = amax[j >> 3] * (1.0f / 7.0f);
    f16x8 o;
    o[0] = (f16)((float)a.x * s); o[1] = (f16)((float)a.y * s);
    o[2] = (f16)((float)a.z * s); o[3] = (f16)((float)a.w * s);
    o[4] = (f16)((float)b.x * s); o[5] = (f16)((float)b.y * s);
    o[6] = (f16)((float)b.z * s); o[7] = (f16)((float)b.w * s);
    *(f16x8*)(wo + (size_t)j * 8) = o;
  }
}

// LDS half-slots of 16KB: A(parity ap in {0,32768,65536}, khalf kk) @ ap + kk*16384;
// B(parity p, khalf kk) @ AB_OFF + p*32768 + kk*16384.
// Half-slot: 256 rows x 32 f16 as [128 ldsrows][128B], swizzle c' = c ^ ((r&7)<<4).
__global__ __launch_bounds__(512, 2) void gemm_f16_bt(const f16* __restrict__ A,
                                                      const f16* __restrict__ B,
                                                      const float* __restrict__ bias,
                                                      float* __restrict__ C) {
  __shared__ __align__(16) char lds[163840];

  const int tid = threadIdx.x;
  const int w = tid >> 6;
  const int l = tid & 63;
  const int wr = w >> 2;  // 0..1 : 128 M-rows each
  const int wc = w & 3;   // 0..3 : 64 N-cols each

  // bijective XCD swizzle: nwg = 1376 = 8 * 172
  const int wg = blockIdx.x;
  const int swz = (wg & 7) * 172 + (wg >> 3);
  const int mt = swz / 43;
  const int nt = swz % 43;
  const int m0 = mt * 256;
  const int n0 = nt * 256;

  // 32x32 fragment lane terms: ra = R0 + (l&31), kb bytes = ks*32 + (l>>5)*16
  const int l31 = l & 31;
  const int lbase = (l31 >> 1) << 7;
  const int lxor = ((l31 >> 1) & 7) << 4;
  const int lk0 = ((l & 1) << 6) | ((l >> 5) << 4);
  const int lt0 = lk0 ^ lxor;         // ks = 0
  const int lt1 = (lk0 | 32) ^ lxor;  // ks = 1

  // pre-swizzled staging sources: wave w stages 1KB chunks w and w+8 of each 16KB half-slot
  const char* AsrcP[2];
  const char* BsrcP[2];
#pragma unroll
  for (int j = 0; j < 2; ++j) {
    const int u = ((w + j * 8) << 10) + l * 16;
    const int r = u >> 7;
    const int cp = (u & 127) ^ ((r & 7) << 4);
    const int ra = 2 * r + (cp >> 6);
    const int kb = cp & 63;
    AsrcP[j] = (const char*)A + (size_t)(m0 + ra) * (K_DIM * 2) + kb;
    BsrcP[j] = (const char*)B + (size_t)(n0 + ra) * (K_DIM * 2) + kb;
  }

  char* ldsc = (char*)lds;

#define STAGE_A(dst_off, koff)              \
  {                                         \
    char* d_ = ldsc + (dst_off) + w * 1024; \
    gload16(AsrcP[0] + (koff), d_);         \
    gload16(AsrcP[1] + (koff), d_ + 8192);  \
  }
#define STAGE_B(dst_off, koff)              \
  {                                         \
    char* d_ = ldsc + (dst_off) + w * 1024; \
    gload16(BsrcP[0] + (koff), d_);         \
    gload16(BsrcP[1] + (koff), d_ + 8192);  \
  }

  f32x16 acc[4][2];
#pragma unroll
  for (int i = 0; i < 4; ++i)
#pragma unroll
    for (int j = 0; j < 2; ++j) acc[i][j] = (f32x16)0.f;

  const int aW = wr * 8192;  // (wr*64 ldsrows) * 128B
  const int bW = wc * 4096;  // (wc*32 ldsrows) * 128B

  // prologue: Alo0,Ahi0,Blo0,Bhi0,Alo1,Ahi1,Blo1 = 14 loads; vmcnt(6) confirms tile 0.
  STAGE_A(0, 0);
  STAGE_A(16384, 64);
  STAGE_B(AB_OFF, 0);
  STAGE_B(AB_OFF + 16384, 64);
  STAGE_A(32768, 128);
  STAGE_A(32768 + 16384, 192);
  STAGE_B(AB_OFF + 32768, 128);
  asm volatile("s_waitcnt vmcnt(6)" ::: "memory");
  __builtin_amdgcn_s_barrier();

  int ap = 0;       // A parity base of tile t
  int ap2 = 65536;  // A parity base of tile t+2

  for (int t = 0; t < NT_K; ++t) {
    const int p = t & 1;
    const int pn = p ^ 1;
    const int Bb = AB_OFF + p * 32768;
    const int Bn = AB_OFF + pn * 32768;
    const int t1 = (t + 1 < NT_K) ? (t + 1) : (NT_K - 1);
    const int t2 = (t + 2 < NT_K) ? (t + 2) : (NT_K - 1);
    const int k1 = t1 * 128;
    const int k2 = t2 * 128;

#pragma unroll
    for (int pi = 0; pi < 4; ++pi) {
      const int kk = pi >> 1;
      const int kt = (pi & 1) ? lt1 : lt0;

      f16x8 af[4], bf[2];
#pragma unroll
      for (int mf = 0; mf < 4; ++mf)
        af[mf] = *(const f16x8*)(ldsc + ap + kk * 16384 + aW + mf * 2048 + lbase + kt);
#pragma unroll
      for (int nf = 0; nf < 2; ++nf)
        bf[nf] = *(const f16x8*)(ldsc + Bb + kk * 16384 + bW + nf * 2048 + lbase + kt);

      if (pi == 0) {
        STAGE_B(Bn + 16384, k1 + 64);   // Bhi[t+1] -> parity pn (untouched by tile t)
      } else if (pi == 1) {
        STAGE_A(ap2, k2);               // Alo[t+2] -> free A parity
      } else if (pi == 2) {
        STAGE_A(ap2 + 16384, k2 + 64);  // Ahi[t+2]
      } else {
        STAGE_B(Bb, k2);                // Blo[t+2] -> B[p][kk0], last read in ph1
      }

      __builtin_amdgcn_s_barrier();
      asm volatile("s_waitcnt lgkmcnt(0)" ::: "memory");  // dense read burst fully landed
      __builtin_amdgcn_sched_barrier(0);                  // rule #18: pin MFMA below the wait
      __builtin_amdgcn_s_setprio(1);
#pragma unroll
      for (int mf = 0; mf < 4; ++mf)
#pragma unroll
        for (int nf = 0; nf < 2; ++nf)
          acc[mf][nf] = __builtin_amdgcn_mfma_f32_32x32x16_f16(af[mf], bf[nf], acc[mf][nf], 0, 0, 0);
      __builtin_amdgcn_s_setprio(0);
      if (pi == 3) asm volatile("s_waitcnt vmcnt(6)" ::: "memory");  // confirms tile t+1
      __builtin_amdgcn_s_barrier();
    }

    ap += 32768;  if (ap == AB_OFF) ap = 0;
    ap2 += 32768; if (ap2 == AB_OFF) ap2 = 0;
  }

  // epilogue: 32x32 C/D layout col = lane&31, row = (reg&3) + 8*(reg>>2) + 4*(lane>>5)
  const int rbase = 4 * (l >> 5);
  float bv[2];
#pragma unroll
  for (int nf = 0; nf < 2; ++nf) bv[nf] = bias[n0 + wc * 64 + nf * 32 + l31];
#pragma unroll
  for (int mf = 0; mf < 4; ++mf) {
#pragma unroll
    for (int nf = 0; nf < 2; ++nf) {
      const size_t col = n0 + wc * 64 + nf * 32 + l31;
#pragma unroll
      for (int q = 0; q < 4; ++q) {
#pragma unroll
        for (int j = 0; j < 4; ++j) {
          const int row = m0 + wr * 128 + mf * 32 + rbase + 8 * q + j;
          __builtin_nontemporal_store(acc[mf][nf][q * 4 + j] + bv[nf],
                                      &C[(size_t)row * N_DIM + col]);
        }
      }
    }
  }
#undef STAGE_A
#undef STAGE_B
}

extern "C" void kernel_launch(void* const* d_in, const int* in_sizes, int n_in,
                              void* d_out, int out_size, void* d_ws, size_t ws_size,
                              hipStream_t stream) {
  const float* x = (const float*)d_in[0];
  const int* wq = (const int*)d_in[1];
  const float* amax = (const float*)d_in[2];
  const float* bias = (const float*)d_in[3];
  float* out = (float*)d_out;

  f16* Xh = (f16*)d_ws;                                       // 64 MB
  f16* Wh = (f16*)((char*)d_ws + (size_t)M_DIM * K_DIM * 2);  // 90 MB

  {
    int n8x = M_DIM * K_DIM / 8;  // 4194304 (multiple of 256 -> no mixed block)
    int n8w = N_DIM * K_DIM / 8;  // 5636096
    int nthr = n8x + n8w;
    prep_kernel<<<(nthr + 255) / 256, 256, 0, stream>>>(x, Xh, n8x, wq, amax, Wh, n8w);
  }
  {
    dim3 grid((M_DIM / 256) * (N_DIM / 256));  // 32*43 = 1376
    gemm_f16_bt<<<grid, 512, 0, stream>>>(Xh, Wh, bias, out);
  }
}